// Round 11
// baseline (132.678 us; speedup 1.0000x reference)
//
#include <hip/hip_runtime.h>

#define NEG_INF (-__builtin_huge_valf())

// -inf virtual row: out-of-image x rows redirect here with c-stride 0.
// Only aligned float4 loads at cols w0..w0+3 (w0<=60) -> 64 floats suffice.
#define N8 NEG_INF,NEG_INF,NEG_INF,NEG_INF,NEG_INF,NEG_INF,NEG_INF,NEG_INF
__constant__ __align__(16) float NINF_ROW[64] = {N8,N8,N8,N8,N8,N8,N8,N8};
#undef N8

typedef float v2f __attribute__((ext_vector_type(2)));

// DPP row-shifts across the 16-lane row (one hr group). bound_ctrl=0 keeps
// `old` (-inf) for boundary lanes: w-halo for free. Verified R8 (absmax 0).
__device__ __forceinline__ float dpp_shr1(float v, float old) {   // wg <- wg-1
    return __int_as_float(__builtin_amdgcn_update_dpp(
        __float_as_int(old), __float_as_int(v), 0x111, 0xF, 0xF, false));
}
__device__ __forceinline__ float dpp_shl1(float v, float old) {   // wg <- wg+1
    return __int_as_float(__builtin_amdgcn_update_dpp(
        __float_as_int(old), __float_as_int(v), 0x101, 0xF, 0xF, false));
}

// c-split, LDS-free, barrier-free. Block = 64 threads = 1 wave; thread =
// 2o x 1h x 4w = 8 acc over c_count channels. grid.z encodes (c-half, o-pair):
// half = z>>5 -> dst/out half, o_pair = z&31. 8192 waves when split -> 32
// waves/CU; every stall class is per-wave and hidden by 7+ co-resident waves.
__global__ __launch_bounds__(64, 4)
void maxplus_conv2d_kernel(const float* __restrict__ x,
                           const float* __restrict__ kern,
                           float* __restrict__ out0,
                           float* __restrict__ out1,
                           int c_count) {
    const int tid = threadIdx.x;        // 0..63
    const int wg  = tid & 15;
    const int hr  = tid >> 4;           // 0..3
    const int w0  = wg << 2;

    const int h      = blockIdx.x * 4 + hr;
    const int b      = blockIdx.y;
    const int half   = blockIdx.z >> 5;
    const int o_base = (blockIdx.z & 31) << 1;
    const int c0     = half * c_count;
    float* dst       = half ? out1 : out0;

    // per-row pointers at (c0, row, w0); invalid rows -> NINF_ROW, stride 0
    const float* xb = x + (size_t)b * 64 * 64 * 64 + (size_t)c0 * 64 * 64;
    const float* p[3];
    int strd[3];
#pragma unroll
    for (int r = 0; r < 3; ++r) {
        int gh = h - 1 + r;
        bool valid = (unsigned)gh < 64u;
        p[r]    = valid ? (xb + (size_t)gh * 64 + w0) : (NINF_ROW + w0);
        strd[r] = valid ? 4096 : 0;
    }

    const float ninf = NEG_INF;

    float acc[2][4];
#pragma unroll
    for (int oo = 0; oo < 2; ++oo)
#pragma unroll
        for (int wi = 0; wi < 4; ++wi)
            acc[oo][wi] = NEG_INF;

    // 2-stage pipeline: x quads + taps prefetched one c ahead
    float4 Aq[3], Bq[3];
    float kvA[2][9], kvB[2][9];
#pragma unroll
    for (int r = 0; r < 3; ++r) Aq[r] = *(const float4*)p[r];
#pragma unroll
    for (int oo = 0; oo < 2; ++oo) {
        const float* kp = kern + ((size_t)(o_base + oo) * 64 + c0) * 9;
#pragma unroll
        for (int t = 0; t < 9; ++t) kvA[oo][t] = kp[t];
    }

#pragma unroll 1
    for (int c = 0; c < c_count; ++c) {
        const bool more = (c + 1 < c_count);
        if (more) {   // uniform branch: prefetch c+1
#pragma unroll
            for (int r = 0; r < 3; ++r) {
                p[r] += strd[r];
                Bq[r] = *(const float4*)p[r];
            }
#pragma unroll
            for (int oo = 0; oo < 2; ++oo) {
                const float* kp = kern + ((size_t)(o_base + oo) * 64 + (c0 + c + 1)) * 9;
#pragma unroll
                for (int t = 0; t < 9; ++t) kvB[oo][t] = kp[t];
            }
        }

        // ---- compute on Aq/kvA (R8's proven pk/DPP core) ----
#pragma unroll
        for (int r = 0; r < 3; ++r) {
            float4 m = Aq[r];
            float le = dpp_shr1(m.w, ninf);   // col w0-1 (wg==0 -> -inf)
            float re = dpp_shl1(m.x, ninf);   // col w0+4 (wg==15 -> -inf)

            v2f P0 = {le,  m.x};   // window idx (0,1)
            v2f P1 = {m.y, m.z};   // (2,3)
            v2f P2 = {m.w, re };   // (4,5)
            v2f Q0 = {m.x, m.y};   // (1,2)
            v2f Q1 = {m.z, m.w};   // (3,4)

#pragma unroll
            for (int oo = 0; oo < 2; ++oo) {
                const float* k9 = kvA[oo];
                v2f ka = {k9[3*r+0], k9[3*r+0]};
                v2f kb = {k9[3*r+1], k9[3*r+1]};
                v2f kc = {k9[3*r+2], k9[3*r+2]};
                v2f a0 = P0 + ka, b0 = P1 + ka;   // kj=0
                v2f a1 = Q0 + kb, b1 = Q1 + kb;   // kj=1
                v2f a2 = P1 + kc, b2 = P2 + kc;   // kj=2

                acc[oo][0] = fmaxf(acc[oo][0], fmaxf(fmaxf(a0.x, a1.x), a2.x));
                acc[oo][1] = fmaxf(acc[oo][1], fmaxf(fmaxf(a0.y, a1.y), a2.y));
                acc[oo][2] = fmaxf(acc[oo][2], fmaxf(fmaxf(b0.x, b1.x), b2.x));
                acc[oo][3] = fmaxf(acc[oo][3], fmaxf(fmaxf(b0.y, b1.y), b2.y));
            }
        }

        if (more) {   // rotate pipeline
#pragma unroll
            for (int r = 0; r < 3; ++r) Aq[r] = Bq[r];
#pragma unroll
            for (int oo = 0; oo < 2; ++oo)
#pragma unroll
                for (int t = 0; t < 9; ++t) kvA[oo][t] = kvB[oo][t];
        }
    }

#pragma unroll
    for (int oo = 0; oo < 2; ++oo) {
        float4 v = make_float4(acc[oo][0], acc[oo][1], acc[oo][2], acc[oo][3]);
        *(float4*)(dst + ((((size_t)b * 64 + (o_base + oo)) * 64 + h) * 64 + w0)) = v;
    }
}

__global__ __launch_bounds__(256)
void merge_max_kernel(float* __restrict__ out, const float* __restrict__ ws, int n4) {
    int i = blockIdx.x * 256 + threadIdx.x;
    if (i < n4) {
        float4 a = ((const float4*)out)[i];
        float4 b = ((const float4*)ws)[i];
        a.x = fmaxf(a.x, b.x); a.y = fmaxf(a.y, b.y);
        a.z = fmaxf(a.z, b.z); a.w = fmaxf(a.w, b.w);
        ((float4*)out)[i] = a;
    }
}

extern "C" void kernel_launch(void* const* d_in, const int* in_sizes, int n_in,
                              void* d_out, int out_size, void* d_ws, size_t ws_size,
                              hipStream_t stream) {
    const float* x    = (const float*)d_in[0];   // [8,64,64,64]
    const float* kern = (const float*)d_in[1];   // [64,64,3,3]
    float* out = (float*)d_out;                  // [8,64,64,64] = 2097152 floats
    float* ws  = (float*)d_ws;

    const bool split = ws_size >= (size_t)out_size * sizeof(float);
    if (split) {
        dim3 grid(16, 8, 64);   // h-tiles, b, (c-half | o-pair)
        maxplus_conv2d_kernel<<<grid, dim3(64), 0, stream>>>(x, kern, out, ws, 32);
        int n4 = out_size / 4;
        merge_max_kernel<<<(n4 + 255) / 256, dim3(256), 0, stream>>>(out, ws, n4);
    } else {
        dim3 grid(16, 8, 32);   // unsplit fallback: full c range into out
        maxplus_conv2d_kernel<<<grid, dim3(64), 0, stream>>>(x, kern, out, out, 64);
    }
}